// Round 12
// baseline (239.061 us; speedup 1.0000x reference)
//
#include <hip/hip_runtime.h>
#include <hip/hip_bf16.h>

// Node_EncodingBlock on MI355X. Inputs fp32, output fp32.
// R12: k_ffn rebuilt with all three required properties simultaneously:
//   (1) weights read ONCE per block (R9's 2-row read them twice),
//   (2) explicit 4-deep float4 load batches, 16 FMA/load (R10's VGPR=40
//       showed compiler re-serialization without this),
//   (3) 46KB LDS -> 3 blocks/CU (R11's 88KB gave 1/CU).
// 500 blocks x 4 rows; GEMM1 k-split 4, GEMM2 k-split 16, 32KB partial union.
// k_red widened to 32 blocks. Ghost launches (same codegen, %500 grid,
// scratch bases) at x10/x5/x10 surface all three kernels in top-5.

#define BN_EPS 1e-5f
// ws float offsets
#define WS_X1    256000     // [2000][128]
#define WS_X2    512000     // [2000][128]
#define WS_SUM1  768000     // [128]+[128] SQ1 contiguous
#define WS_SQ1   768128
#define WS_SUM2  768256
#define WS_SQ2   768384
#define WS_UV    768512
#define WS_C0V   768640
#define BN1P     770000     // [500][256]
#define BN2P     900000     // [500][256]
// ghost scratch (never read)
#define G_X1     1100000    // [2000][128]; also ghost-final out
#define G_BN1P   1400000    // [500][256]; also ghost-ffn BN2 partials
#define G_X2     1600000    // [2000][128]

// 2-row GEMM micro-step (attn phase D / final)
#define GB8_R2(WPTR, LDW, KIDX, ACT2D, ACC)                             \
  {                                                                     \
    float4 w[8];                                                        \
    _Pragma("unroll")                                                   \
    for (int u = 0; u < 8; ++u)                                         \
      w[u] = *(const float4*)((WPTR) + (size_t)((KIDX) + u) * (LDW));   \
    _Pragma("unroll")                                                   \
    for (int u = 0; u < 8; ++u) {                                       \
      _Pragma("unroll")                                                 \
      for (int r = 0; r < 2; ++r) {                                     \
        float a = ACT2D[r][u];                                          \
        ACC[r][0] = fmaf(a, w[u].x, ACC[r][0]);                         \
        ACC[r][1] = fmaf(a, w[u].y, ACC[r][1]);                         \
        ACC[r][2] = fmaf(a, w[u].z, ACC[r][2]);                         \
        ACC[r][3] = fmaf(a, w[u].w, ACC[r][3]);                         \
      }                                                                 \
    }                                                                   \
  }

#define LD_AV2(SRC_ROW0, SRC_ROW1, KIDX, ACT2D)                         \
  {                                                                     \
    float4 x0 = *(const float4*)&(SRC_ROW0)[(KIDX)];                    \
    float4 y0 = *(const float4*)&(SRC_ROW0)[(KIDX) + 4];                \
    float4 x1 = *(const float4*)&(SRC_ROW1)[(KIDX)];                    \
    float4 y1 = *(const float4*)&(SRC_ROW1)[(KIDX) + 4];                \
    ACT2D[0][0]=x0.x; ACT2D[0][1]=x0.y; ACT2D[0][2]=x0.z; ACT2D[0][3]=x0.w; \
    ACT2D[0][4]=y0.x; ACT2D[0][5]=y0.y; ACT2D[0][6]=y0.z; ACT2D[0][7]=y0.w; \
    ACT2D[1][0]=x1.x; ACT2D[1][1]=x1.y; ACT2D[1][2]=x1.z; ACT2D[1][3]=x1.w; \
    ACT2D[1][4]=y1.x; ACT2D[1][5]=y1.y; ACT2D[1][6]=y1.z; ACT2D[1][7]=y1.w; \
  }

// 4-row x 4-col x 4-k batch: 4 independent float4 weight loads, 64 FMAs.
#define GB4_R4(WPTR, LDW, K0, SRC2D, ACC)                               \
  {                                                                     \
    float4 w[4];                                                        \
    _Pragma("unroll")                                                   \
    for (int u = 0; u < 4; ++u)                                         \
      w[u] = *(const float4*)((WPTR) + (size_t)((K0) + u) * (LDW));     \
    float av[4][4];                                                     \
    _Pragma("unroll")                                                   \
    for (int r = 0; r < 4; ++r) {                                       \
      float4 x = *(const float4*)&SRC2D[r][(K0)];                       \
      av[r][0] = x.x; av[r][1] = x.y; av[r][2] = x.z; av[r][3] = x.w;   \
    }                                                                   \
    _Pragma("unroll")                                                   \
    for (int u = 0; u < 4; ++u) {                                       \
      _Pragma("unroll")                                                 \
      for (int r = 0; r < 4; ++r) {                                     \
        ACC[r][0] = fmaf(av[r][u], w[u].x, ACC[r][0]);                  \
        ACC[r][1] = fmaf(av[r][u], w[u].y, ACC[r][1]);                  \
        ACC[r][2] = fmaf(av[r][u], w[u].z, ACC[r][2]);                  \
        ACC[r][3] = fmaf(av[r][u], w[u].w, ACC[r][3]);                  \
      }                                                                 \
    }                                                                   \
  }

// ---- kA: attention + multi_head_combine + BN1 partials --------------------
__global__ __launch_bounds__(512, 4) void k_attn(const float* __restrict__ cost,
                                                 const float* __restrict__ rnd,
                                                 const float* __restrict__ Wv,
                                                 const float* __restrict__ mix1w,
                                                 const float* __restrict__ mix1b,
                                                 const float* __restrict__ mix2w,
                                                 const float* __restrict__ mix2b,
                                                 const float* __restrict__ Wo,
                                                 const float* __restrict__ bo,
                                                 float* __restrict__ ws,
                                                 int xbase, int pbase) {
  __shared__ float scost[4][512];
  __shared__ float2 lut[8 * 256];
  __shared__ float aw[32][132];
  __shared__ float soc[4][132];
  __shared__ float sP[8][512];
  __shared__ float svr[128];
  __shared__ int   sperm[128];
  __shared__ float mu[8][16], mr[8][16], mA[8], mB[8];
  __shared__ float sS[512], sQ[512];
  const int t = threadIdx.x;
  const int lane = t & 63;
  const int blk = blockIdx.x % 500;
  const int row0 = blk * 4;
  const int b = blk / 125;

  {
    int rr = t >> 7, i4 = t & 127;
    *(float4*)&scost[rr][i4 * 4] = (i4 < 125)
        ? *(const float4*)(cost + (size_t)(row0 + rr) * 500 + i4 * 4)
        : float4{0.f, 0.f, 0.f, 0.f};
  }
  if (t < 128) svr[t] = rnd[b * 128 + t];
  __syncthreads();
  if (t < 128) {
    float vt = svr[t];
    int rank = 0;
    for (int j = 0; j < 128; ++j) {
      float vj = svr[j];
      rank += (vj < vt) || (vj == vt && j < t);
    }
    sperm[rank] = t;
    int h = t >> 4, s = t & 15;
    float w1  = mix1w[h * 32 + 16 + s];
    float b1v = mix1b[h * 16 + s];
    float w2  = mix2w[h * 16 + s];
    bool tiny = fabsf(w1) < 1e-20f;
    float us = tiny ? 0.f : 0.5f * w2 * fabsf(w1);
    float rs = tiny ? 0.f : -b1v / w1;
    float Ap = 0.5f * w2 * w1;
    float Bp = 0.5f * w2 * b1v + (tiny ? 0.5f * w2 * fabsf(b1v) : 0.f);
    mu[h][s] = us; mr[h][s] = rs;
#pragma unroll
    for (int off = 1; off < 16; off <<= 1) {
      Ap += __shfl_xor(Ap, off);
      Bp += __shfl_xor(Bp, off);
    }
    if (s == 0) { mA[h] = Ap; mB[h] = Bp + mix2b[h]; }
  }
  __syncthreads();
  float* traw = &sP[0][0];
  if (t < 257) {
    float x = (float)t * (1.f / 255.f);
    for (int h = 0; h < 8; ++h) {
      float g = fmaf(x, mA[h], mB[h]);
#pragma unroll
      for (int s = 0; s < 16; ++s)
        g = fmaf(fabsf(x - mr[h][s]), mu[h][s], g);
      traw[h * 257 + t] = __expf(g);
    }
  }
  __syncthreads();
#pragma unroll
  for (int p = 0; p < 4; ++p) {
    int e = t + p * 512;
    int h = e >> 8, i = e & 255;
    float a = traw[h * 257 + i];
    lut[e] = float2{a, traw[h * 257 + i + 1] - a};
  }
  __syncthreads();
  {
    const int wid = t >> 6;
    const int r  = wid & 3;
    const int h0 = (wid >> 2) * 4;
    float cv8[8];
#pragma unroll
    for (int ii = 0; ii < 8; ++ii) cv8[ii] = scost[r][ii * 64 + lane];
    for (int h = h0; h < h0 + 4; ++h) {
      const float2* lh = &lut[h * 256];
      float wsum = 0.f, a0 = 0.f, a1 = 0.f;
#pragma unroll
      for (int ii = 0; ii < 8; ++ii) {
        float u = cv8[ii] * 255.f;
        int i = (int)u;
        float f = u - (float)i;
        float2 td = lh[i];
        float e = fmaf(td.y, f, td.x);
        if (ii == 7 && lane >= 52) e = 0.f;
        wsum += e;
        if (ii & 1) a1 += e; else a0 += e;
      }
#pragma unroll
      for (int off = 32; off; off >>= 1) wsum += __shfl_xor(wsum, off);
      float inv = 1.f / wsum;
      aw[r * 8 + h][lane]      = a0 * inv;
      aw[r * 8 + h][64 + lane] = a1 * inv;
    }
  }
  __syncthreads();
  {
    const int c  = t & 127;
    const int jh = t >> 7;
    const int h  = c >> 4;
    float acc4[4] = {0.f, 0.f, 0.f, 0.f};
    for (int jb = jh * 32; jb < jh * 32 + 32; jb += 8) {
      int rows[8];
#pragma unroll
      for (int u = 0; u < 8; ++u) rows[u] = sperm[jb + u];
      float wv8[8];
#pragma unroll
      for (int u = 0; u < 8; ++u) wv8[u] = Wv[(size_t)rows[u] * 128 + c];
#pragma unroll
      for (int r = 0; r < 4; ++r) {
        float4 aa = *(const float4*)&aw[r * 8 + h][jb];
        float4 ab = *(const float4*)&aw[r * 8 + h][jb + 4];
        acc4[r] = fmaf(aa.x, wv8[0], acc4[r]);
        acc4[r] = fmaf(aa.y, wv8[1], acc4[r]);
        acc4[r] = fmaf(aa.z, wv8[2], acc4[r]);
        acc4[r] = fmaf(aa.w, wv8[3], acc4[r]);
        acc4[r] = fmaf(ab.x, wv8[4], acc4[r]);
        acc4[r] = fmaf(ab.y, wv8[5], acc4[r]);
        acc4[r] = fmaf(ab.z, wv8[6], acc4[r]);
        acc4[r] = fmaf(ab.w, wv8[7], acc4[r]);
      }
    }
#pragma unroll
    for (int r = 0; r < 4; ++r) sP[jh][r * 128 + c] = acc4[r];
  }
  __syncthreads();
  {
    int r = t >> 7, c = t & 127;
    soc[r][c] = sP[0][r * 128 + c] + sP[1][r * 128 + c] +
                sP[2][r * 128 + c] + sP[3][r * 128 + c];
  }
  __syncthreads();
  {
    const int cg  = (t & 31) * 4;
    const int seg = (t >> 5) & 7;
    const int rh  = t >> 8;
    const int k0  = seg * 16;
    float acc[2][4] = {};
    float av[2][8];
#pragma unroll
    for (int kb = 0; kb < 16; kb += 8) {
      LD_AV2(soc[rh * 2], soc[rh * 2 + 1], k0 + kb, av);
      GB8_R2(Wo + cg, 128, k0 + kb, av, acc);
    }
#pragma unroll
    for (int r = 0; r < 2; ++r)
      *(float4*)&sP[seg][(rh * 2 + r) * 128 + cg] = *(float4*)acc[r];
  }
  __syncthreads();
  {
    int r = t >> 7, col = t & 127;
    float x = bo[col];
#pragma unroll
    for (int sg = 0; sg < 8; ++sg) x += sP[sg][r * 128 + col];
    ws[xbase + (size_t)(row0 + r) * 128 + col] = x;
    sS[t] = x; sQ[t] = x * x;
  }
  __syncthreads();
  if (t < 128) {
    ws[pbase + blk * 256 + t]       = sS[t] + sS[t+128] + sS[t+256] + sS[t+384];
    ws[pbase + blk * 256 + 128 + t] = sQ[t] + sQ[t+128] + sQ[t+256] + sQ[t+384];
  }
}

// ---- k_red: 32 blocks reduce partials; block 32 (if present): U/C0 --------
__global__ __launch_bounds__(256) void k_red(const float* __restrict__ Wn,
                                             const float* __restrict__ Wd,
                                             const float* __restrict__ bd,
                                             const float* __restrict__ bnn,
                                             float* __restrict__ ws,
                                             int src, int nslots, int dst) {
  const int t = threadIdx.x;
  if (blockIdx.x < 32) {
    __shared__ float red[32][9];
    const int col = blockIdx.x * 8 + (t & 7);
    const int strip = t >> 3;          // 0..31
    float s = 0.f;
    for (int j = strip; j < nslots; j += 32) s += ws[src + j * 256 + col];
    red[strip][t & 7] = s;
    __syncthreads();
    if (t < 8) {
      float x = 0.f;
#pragma unroll
      for (int k = 0; k < 32; ++k) x += red[k][t];
      ws[dst + blockIdx.x * 8 + t] = x;
    }
  } else {
    __shared__ float ru[2][128], rc[2][128];
    const int c = t & 127, g = t >> 7;
    float u = 0.f, cc = 0.f;
#pragma unroll 8
    for (int e = g * 64; e < g * 64 + 64; ++e) {
      float wn = Wn[(size_t)(128 + e) * 128 + c];
      u  = fmaf(Wd[e], wn, u);
      cc = fmaf(bd[e], wn, cc);
    }
    ru[g][c] = u; rc[g][c] = cc;
    __syncthreads();
    if (t < 128) {
      ws[WS_UV + t]  = ru[0][t] + ru[1][t];
      ws[WS_C0V + t] = rc[0][t] + rc[1][t] + bnn[t];
    }
  }
}

// ---- kB: BN1 -> FFN -> X2 + BN2 partials ----------------------------------
// 500 blocks x 512 thr, 4 rows/block. Weights once/block; 46KB LDS (3/CU).
__global__ __launch_bounds__(512, 2) void k_ffn(const float* __restrict__ W1,
                                                const float* __restrict__ b1,
                                                const float* __restrict__ g1,
                                                const float* __restrict__ bb1,
                                                const float* __restrict__ W2,
                                                const float* __restrict__ b2,
                                                float* __restrict__ ws,
                                                int x2base, int p2base) {
  __shared__ float o1[4][128];         // 2 KB
  __shared__ float sY[4][512];         // 8 KB
  __shared__ float sP[4][4][512];      // 32 KB; GEMM2 view [16][4][128]
  __shared__ float sS[512], sQ[512];
  const int t = threadIdx.x;
  const int blk = blockIdx.x % 500;
  const int row0 = blk * 4;
  const int c0 = t & 127;
  float m1 = ws[WS_SUM1 + c0] * 5e-4f;
  float v1 = ws[WS_SQ1 + c0] * 5e-4f - m1 * m1;
  float scv = g1[c0] * rsqrtf(v1 + BN_EPS);
  float shv = bb1[c0] - m1 * scv;
  {
    int r = t >> 7;
    o1[r][c0] = ws[WS_X1 + (size_t)(row0 + r) * 128 + c0] * scv + shv;
  }
  __syncthreads();
  // GEMM1 (128->512): cg(128 x 4cols) x kseg(4 x 32k), 4-row accumulate
  {
    const int cg   = (t & 127) * 4;
    const int kseg = t >> 7;           // 0..3
    const int kb0  = kseg * 32;
    float acc[4][4] = {};
#pragma unroll
    for (int kb = 0; kb < 32; kb += 4)
      GB4_R4(W1 + cg, 512, kb0 + kb, o1, acc);
#pragma unroll
    for (int r = 0; r < 4; ++r)
      *(float4*)&sP[kseg][r][cg] = *(float4*)acc[r];
  }
  __syncthreads();
  // combine + bias + relu -> sY
#pragma unroll
  for (int i = 0; i < 4; ++i) {
    int idx = t + i * 512;             // 0..2047
    int r = idx >> 9, c = idx & 511;
    float x = sP[0][r][c] + sP[1][r][c] + sP[2][r][c] + sP[3][r][c];
    sY[r][c] = fmaxf(x + b1[c], 0.f);
  }
  __syncthreads();
  // GEMM2 (512->128): cg(32 x 4cols) x kseg(16 x 32k), 4-row accumulate
  float* p2 = &sP[0][0][0];            // [16][4][128] view
  {
    const int cg   = (t & 31) * 4;
    const int kseg = t >> 5;           // 0..15
    const int kb0  = kseg * 32;
    float acc[4][4] = {};
#pragma unroll
    for (int kb = 0; kb < 32; kb += 4)
      GB4_R4(W2 + cg, 128, kb0 + kb, sY, acc);
#pragma unroll
    for (int r = 0; r < 4; ++r)
      *(float4*)(p2 + (size_t)(kseg * 4 + r) * 128 + cg) = *(float4*)acc[r];
  }
  __syncthreads();
  // combine + bias + residual -> X2 + BN2 partials
  {
    int r = t >> 7, c = t & 127;
    float x = b2[c] + o1[r][c];
#pragma unroll
    for (int sg = 0; sg < 16; ++sg) x += p2[(size_t)(sg * 4 + r) * 128 + c];
    ws[x2base + (size_t)(row0 + r) * 128 + c] = x;
    sS[t] = x; sQ[t] = x * x;
  }
  __syncthreads();
  if (t < 128) {
    ws[p2base + blk * 256 + t]       = sS[t] + sS[t+128] + sS[t+256] + sS[t+384];
    ws[p2base + blk * 256 + 128 + t] = sQ[t] + sQ[t+128] + sQ[t+256] + sQ[t+384];
  }
}

// ---- kC: BN2 -> out3 @ Wn_top + demand*U + C0 -> out ----------------------
__global__ __launch_bounds__(512, 4) void k_final(const float* __restrict__ Wn,
                                                  const float* __restrict__ g2,
                                                  const float* __restrict__ bb2,
                                                  const float* __restrict__ dem,
                                                  float* __restrict__ outp,
                                                  float* __restrict__ ws) {
  __shared__ float o3[4][132];
  __shared__ float sP[8][4][128];
  const int t = threadIdx.x;
  const int blk = blockIdx.x % 500;
  const int row0 = blk * 4;
  const int c0 = t & 127;
  float m2 = ws[WS_SUM2 + c0] * 5e-4f;
  float v2 = ws[WS_SQ2 + c0] * 5e-4f - m2 * m2;
  float scv = g2[c0] * rsqrtf(v2 + BN_EPS);
  float shv = bb2[c0] - m2 * scv;
  {
    int r = t >> 7;
    o3[r][c0] = ws[WS_X2 + (size_t)(row0 + r) * 128 + c0] * scv + shv;
  }
  __syncthreads();
  {
    const int cg  = (t & 31) * 4;
    const int seg = (t >> 5) & 7;
    const int rh  = t >> 8;
    const int k0  = seg * 16;
    float acc[2][4] = {};
    float av[2][8];
#pragma unroll
    for (int kb = 0; kb < 16; kb += 8) {
      LD_AV2(o3[rh * 2], o3[rh * 2 + 1], k0 + kb, av);
      GB8_R2(Wn + cg, 128, k0 + kb, av, acc);
    }
#pragma unroll
    for (int r = 0; r < 2; ++r)
      *(float4*)&sP[seg][rh * 2 + r][cg] = *(float4*)acc[r];
  }
  __syncthreads();
  {
    int r = t >> 7;
    float x = ws[WS_C0V + c0] + dem[row0 + r] * ws[WS_UV + c0];
#pragma unroll
    for (int sg = 0; sg < 8; ++sg) x += sP[sg][r][c0];
    outp[(size_t)(row0 + r) * 128 + c0] = x;
  }
}

extern "C" void kernel_launch(void* const* d_in, const int* in_sizes, int n_in,
                              void* d_out, int out_size, void* d_ws, size_t ws_size,
                              hipStream_t stream) {
  const float* cost   = (const float*)d_in[0];
  const float* dem    = (const float*)d_in[1];
  const float* rnd    = (const float*)d_in[2];
  // d_in[3] Wq, d_in[4] Wk unused (q == 0)
  const float* Wv     = (const float*)d_in[5];
  const float* mix1w  = (const float*)d_in[6];
  const float* mix1b  = (const float*)d_in[7];
  const float* mix2w  = (const float*)d_in[8];
  const float* mix2b  = (const float*)d_in[9];
  const float* Wo     = (const float*)d_in[10];
  const float* bo     = (const float*)d_in[11];
  const float* W1     = (const float*)d_in[12];
  const float* b1     = (const float*)d_in[13];
  const float* W2     = (const float*)d_in[14];
  const float* b2     = (const float*)d_in[15];
  const float* g1     = (const float*)d_in[16];
  const float* bb1    = (const float*)d_in[17];
  const float* g2     = (const float*)d_in[18];
  const float* bb2    = (const float*)d_in[19];
  const float* Wd     = (const float*)d_in[20];
  const float* bd     = (const float*)d_in[21];
  const float* Wn     = (const float*)d_in[22];
  const float* bnn    = (const float*)d_in[23];
  float* ws  = (float*)d_ws;
  float* out = (float*)d_out;

  // real chain
  hipLaunchKernelGGL(k_attn,  dim3(500), dim3(512), 0, stream, cost, rnd, Wv,
                     mix1w, mix1b, mix2w, mix2b, Wo, bo, ws, WS_X1, BN1P);
  hipLaunchKernelGGL(k_red,   dim3(33),  dim3(256), 0, stream, Wn, Wd, bd, bnn,
                     ws, BN1P, 500, WS_SUM1);
  hipLaunchKernelGGL(k_ffn,   dim3(500), dim3(512), 0, stream, W1, b1, g1, bb1,
                     W2, b2, ws, WS_X2, BN2P);
  hipLaunchKernelGGL(k_red,   dim3(32),  dim3(256), 0, stream, Wn, Wd, bd, bnn,
                     ws, BN2P, 500, WS_SUM2);
  hipLaunchKernelGGL(k_final, dim3(500), dim3(512), 0, stream, Wn, g2, bb2, dem,
                     out, ws);
  // ghosts: identical codegen, scaled grids, scratch outputs (timing probes)
  hipLaunchKernelGGL(k_attn,  dim3(5000), dim3(512), 0, stream, cost, rnd, Wv,
                     mix1w, mix1b, mix2w, mix2b, Wo, bo, ws, G_X1, G_BN1P);
  hipLaunchKernelGGL(k_ffn,   dim3(2500), dim3(512), 0, stream, W1, b1, g1, bb1,
                     W2, b2, ws, G_X2, G_BN1P);
  hipLaunchKernelGGL(k_final, dim3(5000), dim3(512), 0, stream, Wn, g2, bb2, dem,
                     ws + G_X1, ws);
}

// Round 13
// 48.113 us; speedup vs baseline: 4.9688x; 4.9688x over previous
//
#include <hip/hip_runtime.h>
#include <hip/hip_bf16.h>

// Node_EncodingBlock on MI355X. Inputs fp32, output fp32.
// R13: ghosts stripped (R12 telemetry: attn 14.3us @2blk/CU 49% VALU,
// ffn 7.5us (weights-once structure confirmed), final 2.5us).
// k_attn LDS diet 66.5K -> ~49K => 3 blocks/CU:
//   - no scost staging: cost row -> registers at kernel top (coalesced,
//     early-issued so cold HBM fetch overlaps param/LUT phases)
//   - LUT unioned with sP partial pool (lut dead after phase B)
//   - aw keeps 132-pad (rows 128-aligned would 8-way bank-alias)

#define BN_EPS 1e-5f
// ws float offsets
#define WS_X1    256000     // [2000][128]
#define WS_X2    512000     // [2000][128]
#define WS_SUM1  768000
#define WS_SQ1   768128
#define WS_SUM2  768256
#define WS_SQ2   768384
#define WS_UV    768512
#define WS_C0V   768640
#define BN1P     770000     // [500][256]
#define BN2P     900000     // [500][256]

// 2-row GEMM micro-step (attn phase D / final)
#define GB8_R2(WPTR, LDW, KIDX, ACT2D, ACC)                             \
  {                                                                     \
    float4 w[8];                                                        \
    _Pragma("unroll")                                                   \
    for (int u = 0; u < 8; ++u)                                         \
      w[u] = *(const float4*)((WPTR) + (size_t)((KIDX) + u) * (LDW));   \
    _Pragma("unroll")                                                   \
    for (int u = 0; u < 8; ++u) {                                       \
      _Pragma("unroll")                                                 \
      for (int r = 0; r < 2; ++r) {                                     \
        float a = ACT2D[r][u];                                          \
        ACC[r][0] = fmaf(a, w[u].x, ACC[r][0]);                         \
        ACC[r][1] = fmaf(a, w[u].y, ACC[r][1]);                         \
        ACC[r][2] = fmaf(a, w[u].z, ACC[r][2]);                         \
        ACC[r][3] = fmaf(a, w[u].w, ACC[r][3]);                         \
      }                                                                 \
    }                                                                   \
  }

#define LD_AV2(SRC_ROW0, SRC_ROW1, KIDX, ACT2D)                         \
  {                                                                     \
    float4 x0 = *(const float4*)&(SRC_ROW0)[(KIDX)];                    \
    float4 y0 = *(const float4*)&(SRC_ROW0)[(KIDX) + 4];                \
    float4 x1 = *(const float4*)&(SRC_ROW1)[(KIDX)];                    \
    float4 y1 = *(const float4*)&(SRC_ROW1)[(KIDX) + 4];                \
    ACT2D[0][0]=x0.x; ACT2D[0][1]=x0.y; ACT2D[0][2]=x0.z; ACT2D[0][3]=x0.w; \
    ACT2D[0][4]=y0.x; ACT2D[0][5]=y0.y; ACT2D[0][6]=y0.z; ACT2D[0][7]=y0.w; \
    ACT2D[1][0]=x1.x; ACT2D[1][1]=x1.y; ACT2D[1][2]=x1.z; ACT2D[1][3]=x1.w; \
    ACT2D[1][4]=y1.x; ACT2D[1][5]=y1.y; ACT2D[1][6]=y1.z; ACT2D[1][7]=y1.w; \
  }

// 4-row x 4-col x 4-k batch: 4 independent float4 weight loads, 64 FMAs.
#define GB4_R4(WPTR, LDW, K0, SRC2D, ACC)                               \
  {                                                                     \
    float4 w[4];                                                        \
    _Pragma("unroll")                                                   \
    for (int u = 0; u < 4; ++u)                                         \
      w[u] = *(const float4*)((WPTR) + (size_t)((K0) + u) * (LDW));     \
    float av[4][4];                                                     \
    _Pragma("unroll")                                                   \
    for (int r = 0; r < 4; ++r) {                                       \
      float4 x = *(const float4*)&SRC2D[r][(K0)];                       \
      av[r][0] = x.x; av[r][1] = x.y; av[r][2] = x.z; av[r][3] = x.w;   \
    }                                                                   \
    _Pragma("unroll")                                                   \
    for (int u = 0; u < 4; ++u) {                                       \
      _Pragma("unroll")                                                 \
      for (int r = 0; r < 4; ++r) {                                     \
        ACC[r][0] = fmaf(av[r][u], w[u].x, ACC[r][0]);                  \
        ACC[r][1] = fmaf(av[r][u], w[u].y, ACC[r][1]);                  \
        ACC[r][2] = fmaf(av[r][u], w[u].z, ACC[r][2]);                  \
        ACC[r][3] = fmaf(av[r][u], w[u].w, ACC[r][3]);                  \
      }                                                                 \
    }                                                                   \
  }

// ---- kA: attention + multi_head_combine + BN1 partials --------------------
// 500 blocks x 512 thr, 4 rows/block. ~49KB LDS -> 3 blocks/CU.
__global__ __launch_bounds__(512, 6) void k_attn(const float* __restrict__ cost,
                                                 const float* __restrict__ rnd,
                                                 const float* __restrict__ Wv,
                                                 const float* __restrict__ mix1w,
                                                 const float* __restrict__ mix1b,
                                                 const float* __restrict__ mix2w,
                                                 const float* __restrict__ mix2b,
                                                 const float* __restrict__ Wo,
                                                 const float* __restrict__ bo,
                                                 float* __restrict__ ws) {
  __shared__ float pool[6152];   // [0:2056) traw | [2056:6152) lut ; C/D: sP[8][512]
  __shared__ float aw[32][132];
  __shared__ float soc[4][132];
  __shared__ float svr[128];
  __shared__ int   sperm[128];
  __shared__ float mu[8][16], mr[8][16], mA[8], mB[8];
  __shared__ float sS[512], sQ[512];
  const int t = threadIdx.x;
  const int lane = t & 63;
  const int blk = blockIdx.x;
  const int row0 = blk * 4;
  const int b = blk / 125;

  // early cost loads: wave (r, head-half) reads its row into registers.
  // Issued first so the cold HBM fetch overlaps param setup + LUT build.
  const int wr = (t >> 6) & 3;
  float cv8[8];
  {
    const float* crow = cost + (size_t)(row0 + wr) * 500;
#pragma unroll
    for (int ii = 0; ii < 8; ++ii) {
      int m = ii * 64 + lane;
      cv8[ii] = crow[m < 500 ? m : 499];
    }
  }
  if (t < 128) svr[t] = rnd[b * 128 + t];
  __syncthreads();
  if (t < 128) {
    float vt = svr[t];
    int rank = 0;
    for (int j = 0; j < 128; ++j) {
      float vj = svr[j];
      rank += (vj < vt) || (vj == vt && j < t);
    }
    sperm[rank] = t;
    // abs-form MLP params: g(c) = A c + B + sum u_s |c - r_s|
    int h = t >> 4, s = t & 15;
    float w1  = mix1w[h * 32 + 16 + s];
    float b1v = mix1b[h * 16 + s];
    float w2  = mix2w[h * 16 + s];
    bool tiny = fabsf(w1) < 1e-20f;
    float us = tiny ? 0.f : 0.5f * w2 * fabsf(w1);
    float rs = tiny ? 0.f : -b1v / w1;
    float Ap = 0.5f * w2 * w1;
    float Bp = 0.5f * w2 * b1v + (tiny ? 0.5f * w2 * fabsf(b1v) : 0.f);
    mu[h][s] = us; mr[h][s] = rs;
#pragma unroll
    for (int off = 1; off < 16; off <<= 1) {
      Ap += __shfl_xor(Ap, off);
      Bp += __shfl_xor(Bp, off);
    }
    if (s == 0) { mA[h] = Ap; mB[h] = Bp + mix2b[h]; }
  }
  __syncthreads();
  // LUT pass 1: traw[h][i] = exp(g_h(i/255))
  float* traw = pool;
  float2* lut = (float2*)(pool + 2056);
  if (t < 257) {
    float x = (float)t * (1.f / 255.f);
    for (int h = 0; h < 8; ++h) {
      float g = fmaf(x, mA[h], mB[h]);
#pragma unroll
      for (int s = 0; s < 16; ++s)
        g = fmaf(fabsf(x - mr[h][s]), mu[h][s], g);
      traw[h * 257 + t] = __expf(g);
    }
  }
  __syncthreads();
#pragma unroll
  for (int p = 0; p < 4; ++p) {
    int e = t + p * 512;
    int h = e >> 8, i = e & 255;
    float a = traw[h * 257 + i];
    lut[e] = float2{a, traw[h * 257 + i + 1] - a};
  }
  __syncthreads();
  // phase B: wave (wr, head-half): LUT scores -> aggregated softmax weights
  {
    const int h0 = ((t >> 6) >> 2) * 4;
    for (int h = h0; h < h0 + 4; ++h) {
      const float2* lh = &lut[h * 256];
      float wsum = 0.f, a0 = 0.f, a1 = 0.f;
#pragma unroll
      for (int ii = 0; ii < 8; ++ii) {
        float u = cv8[ii] * 255.f;
        int i = (int)u;
        float f = u - (float)i;
        float2 td = lh[i];
        float e = fmaf(td.y, f, td.x);
        if (ii == 7 && lane >= 52) e = 0.f;   // mask m >= 500
        wsum += e;
        if (ii & 1) a1 += e; else a0 += e;
      }
#pragma unroll
      for (int off = 32; off; off >>= 1) wsum += __shfl_xor(wsum, off);
      float inv = 1.f / wsum;
      aw[wr * 8 + h][lane]      = a0 * inv;
      aw[wr * 8 + h][64 + lane] = a1 * inv;
    }
  }
  __syncthreads();
  // phase C: oc[r][c] = sum_j aw[r*8+(c>>4)][j] * Wv[perm[j]][c]; j-split 4
  float* sP = pool;                    // [8][512] view; lut dead from here
  {
    const int c  = t & 127;
    const int jh = t >> 7;
    const int h  = c >> 4;
    float acc4[4] = {0.f, 0.f, 0.f, 0.f};
    for (int jb = jh * 32; jb < jh * 32 + 32; jb += 8) {
      int rows[8];
#pragma unroll
      for (int u = 0; u < 8; ++u) rows[u] = sperm[jb + u];
      float wv8[8];
#pragma unroll
      for (int u = 0; u < 8; ++u) wv8[u] = Wv[(size_t)rows[u] * 128 + c];
#pragma unroll
      for (int r = 0; r < 4; ++r) {
        float4 aa = *(const float4*)&aw[r * 8 + h][jb];
        float4 ab = *(const float4*)&aw[r * 8 + h][jb + 4];
        acc4[r] = fmaf(aa.x, wv8[0], acc4[r]);
        acc4[r] = fmaf(aa.y, wv8[1], acc4[r]);
        acc4[r] = fmaf(aa.z, wv8[2], acc4[r]);
        acc4[r] = fmaf(aa.w, wv8[3], acc4[r]);
        acc4[r] = fmaf(ab.x, wv8[4], acc4[r]);
        acc4[r] = fmaf(ab.y, wv8[5], acc4[r]);
        acc4[r] = fmaf(ab.z, wv8[6], acc4[r]);
        acc4[r] = fmaf(ab.w, wv8[7], acc4[r]);
      }
    }
#pragma unroll
    for (int r = 0; r < 4; ++r) sP[(size_t)jh * 512 + r * 128 + c] = acc4[r];
  }
  __syncthreads();
  {
    int r = t >> 7, c = t & 127;
    soc[r][c] = sP[r * 128 + c] + sP[512 + r * 128 + c] +
                sP[1024 + r * 128 + c] + sP[1536 + r * 128 + c];
  }
  __syncthreads();
  // phase D: X1 = soc @ Wo + bo; k-split 8 x row-half 2
  {
    const int cg  = (t & 31) * 4;
    const int seg = (t >> 5) & 7;
    const int rh  = t >> 8;
    const int k0  = seg * 16;
    float acc[2][4] = {};
    float av[2][8];
#pragma unroll
    for (int kb = 0; kb < 16; kb += 8) {
      LD_AV2(soc[rh * 2], soc[rh * 2 + 1], k0 + kb, av);
      GB8_R2(Wo + cg, 128, k0 + kb, av, acc);
    }
#pragma unroll
    for (int r = 0; r < 2; ++r)
      *(float4*)&sP[(size_t)seg * 512 + (rh * 2 + r) * 128 + cg] = *(float4*)acc[r];
  }
  __syncthreads();
  {
    int r = t >> 7, col = t & 127;
    float x = bo[col];
#pragma unroll
    for (int sg = 0; sg < 8; ++sg) x += sP[(size_t)sg * 512 + r * 128 + col];
    ws[WS_X1 + (size_t)(row0 + r) * 128 + col] = x;
    sS[t] = x; sQ[t] = x * x;
  }
  __syncthreads();
  if (t < 128) {
    ws[BN1P + blk * 256 + t]       = sS[t] + sS[t+128] + sS[t+256] + sS[t+384];
    ws[BN1P + blk * 256 + 128 + t] = sQ[t] + sQ[t+128] + sQ[t+256] + sQ[t+384];
  }
}

// ---- k_red: 32 blocks reduce partials; block 32 (if present): U/C0 --------
__global__ __launch_bounds__(256) void k_red(const float* __restrict__ Wn,
                                             const float* __restrict__ Wd,
                                             const float* __restrict__ bd,
                                             const float* __restrict__ bnn,
                                             float* __restrict__ ws,
                                             int src, int nslots, int dst) {
  const int t = threadIdx.x;
  if (blockIdx.x < 32) {
    __shared__ float red[32][9];
    const int col = blockIdx.x * 8 + (t & 7);
    const int strip = t >> 3;          // 0..31
    float s = 0.f;
    for (int j = strip; j < nslots; j += 32) s += ws[src + j * 256 + col];
    red[strip][t & 7] = s;
    __syncthreads();
    if (t < 8) {
      float x = 0.f;
#pragma unroll
      for (int k = 0; k < 32; ++k) x += red[k][t];
      ws[dst + blockIdx.x * 8 + t] = x;
    }
  } else {
    __shared__ float ru[2][128], rc[2][128];
    const int c = t & 127, g = t >> 7;
    float u = 0.f, cc = 0.f;
#pragma unroll 8
    for (int e = g * 64; e < g * 64 + 64; ++e) {
      float wn = Wn[(size_t)(128 + e) * 128 + c];
      u  = fmaf(Wd[e], wn, u);
      cc = fmaf(bd[e], wn, cc);
    }
    ru[g][c] = u; rc[g][c] = cc;
    __syncthreads();
    if (t < 128) {
      ws[WS_UV + t]  = ru[0][t] + ru[1][t];
      ws[WS_C0V + t] = rc[0][t] + rc[1][t] + bnn[t];
    }
  }
}

// ---- kB: BN1 -> FFN -> X2 + BN2 partials ----------------------------------
// 500 blocks x 512 thr, 4 rows/block. Weights once/block; ~43KB LDS (3/CU).
__global__ __launch_bounds__(512, 2) void k_ffn(const float* __restrict__ W1,
                                                const float* __restrict__ b1,
                                                const float* __restrict__ g1,
                                                const float* __restrict__ bb1,
                                                const float* __restrict__ W2,
                                                const float* __restrict__ b2,
                                                float* __restrict__ ws) {
  __shared__ float o1[4][128];
  __shared__ float sY[4][512];
  __shared__ float sP[4][4][512];      // 32 KB; GEMM2 view [16][4][128]
  __shared__ float sS[512], sQ[512];
  const int t = threadIdx.x;
  const int blk = blockIdx.x;
  const int row0 = blk * 4;
  const int c0 = t & 127;
  float m1 = ws[WS_SUM1 + c0] * 5e-4f;
  float v1 = ws[WS_SQ1 + c0] * 5e-4f - m1 * m1;
  float scv = g1[c0] * rsqrtf(v1 + BN_EPS);
  float shv = bb1[c0] - m1 * scv;
  {
    int r = t >> 7;
    o1[r][c0] = ws[WS_X1 + (size_t)(row0 + r) * 128 + c0] * scv + shv;
  }
  __syncthreads();
  // GEMM1 (128->512): cg(128 x 4cols) x kseg(4 x 32k), 4-row accumulate
  {
    const int cg   = (t & 127) * 4;
    const int kseg = t >> 7;
    const int kb0  = kseg * 32;
    float acc[4][4] = {};
#pragma unroll
    for (int kb = 0; kb < 32; kb += 4)
      GB4_R4(W1 + cg, 512, kb0 + kb, o1, acc);
#pragma unroll
    for (int r = 0; r < 4; ++r)
      *(float4*)&sP[kseg][r][cg] = *(float4*)acc[r];
  }
  __syncthreads();
#pragma unroll
  for (int i = 0; i < 4; ++i) {
    int idx = t + i * 512;
    int r = idx >> 9, c = idx & 511;
    float x = sP[0][r][c] + sP[1][r][c] + sP[2][r][c] + sP[3][r][c];
    sY[r][c] = fmaxf(x + b1[c], 0.f);
  }
  __syncthreads();
  // GEMM2 (512->128): cg(32 x 4cols) x kseg(16 x 32k), 4-row accumulate
  float* p2 = &sP[0][0][0];            // [16][4][128] view
  {
    const int cg   = (t & 31) * 4;
    const int kseg = t >> 5;
    const int kb0  = kseg * 32;
    float acc[4][4] = {};
#pragma unroll
    for (int kb = 0; kb < 32; kb += 4)
      GB4_R4(W2 + cg, 128, kb0 + kb, sY, acc);
#pragma unroll
    for (int r = 0; r < 4; ++r)
      *(float4*)(p2 + (size_t)(kseg * 4 + r) * 128 + cg) = *(float4*)acc[r];
  }
  __syncthreads();
  {
    int r = t >> 7, c = t & 127;
    float x = b2[c] + o1[r][c];
#pragma unroll
    for (int sg = 0; sg < 16; ++sg) x += p2[(size_t)(sg * 4 + r) * 128 + c];
    ws[WS_X2 + (size_t)(row0 + r) * 128 + c] = x;
    sS[t] = x; sQ[t] = x * x;
  }
  __syncthreads();
  if (t < 128) {
    ws[BN2P + blk * 256 + t]       = sS[t] + sS[t+128] + sS[t+256] + sS[t+384];
    ws[BN2P + blk * 256 + 128 + t] = sQ[t] + sQ[t+128] + sQ[t+256] + sQ[t+384];
  }
}

// ---- kC: BN2 -> out3 @ Wn_top + demand*U + C0 -> out ----------------------
__global__ __launch_bounds__(512, 4) void k_final(const float* __restrict__ Wn,
                                                  const float* __restrict__ g2,
                                                  const float* __restrict__ bb2,
                                                  const float* __restrict__ dem,
                                                  float* __restrict__ outp,
                                                  float* __restrict__ ws) {
  __shared__ float o3[4][132];
  __shared__ float sP[8][4][128];
  const int t = threadIdx.x;
  const int blk = blockIdx.x;
  const int row0 = blk * 4;
  const int c0 = t & 127;
  float m2 = ws[WS_SUM2 + c0] * 5e-4f;
  float v2 = ws[WS_SQ2 + c0] * 5e-4f - m2 * m2;
  float scv = g2[c0] * rsqrtf(v2 + BN_EPS);
  float shv = bb2[c0] - m2 * scv;
  {
    int r = t >> 7;
    o3[r][c0] = ws[WS_X2 + (size_t)(row0 + r) * 128 + c0] * scv + shv;
  }
  __syncthreads();
  {
    const int cg  = (t & 31) * 4;
    const int seg = (t >> 5) & 7;
    const int rh  = t >> 8;
    const int k0  = seg * 16;
    float acc[2][4] = {};
    float av[2][8];
#pragma unroll
    for (int kb = 0; kb < 16; kb += 8) {
      LD_AV2(o3[rh * 2], o3[rh * 2 + 1], k0 + kb, av);
      GB8_R2(Wn + cg, 128, k0 + kb, av, acc);
    }
#pragma unroll
    for (int r = 0; r < 2; ++r)
      *(float4*)&sP[seg][rh * 2 + r][cg] = *(float4*)acc[r];
  }
  __syncthreads();
  {
    int r = t >> 7;
    float x = ws[WS_C0V + c0] + dem[row0 + r] * ws[WS_UV + c0];
#pragma unroll
    for (int sg = 0; sg < 8; ++sg) x += sP[sg][r][c0];
    outp[(size_t)(row0 + r) * 128 + c0] = x;
  }
}

extern "C" void kernel_launch(void* const* d_in, const int* in_sizes, int n_in,
                              void* d_out, int out_size, void* d_ws, size_t ws_size,
                              hipStream_t stream) {
  const float* cost   = (const float*)d_in[0];
  const float* dem    = (const float*)d_in[1];
  const float* rnd    = (const float*)d_in[2];
  // d_in[3] Wq, d_in[4] Wk unused (q == 0)
  const float* Wv     = (const float*)d_in[5];
  const float* mix1w  = (const float*)d_in[6];
  const float* mix1b  = (const float*)d_in[7];
  const float* mix2w  = (const float*)d_in[8];
  const float* mix2b  = (const float*)d_in[9];
  const float* Wo     = (const float*)d_in[10];
  const float* bo     = (const float*)d_in[11];
  const float* W1     = (const float*)d_in[12];
  const float* b1     = (const float*)d_in[13];
  const float* W2     = (const float*)d_in[14];
  const float* b2     = (const float*)d_in[15];
  const float* g1     = (const float*)d_in[16];
  const float* bb1    = (const float*)d_in[17];
  const float* g2     = (const float*)d_in[18];
  const float* bb2    = (const float*)d_in[19];
  const float* Wd     = (const float*)d_in[20];
  const float* bd     = (const float*)d_in[21];
  const float* Wn     = (const float*)d_in[22];
  const float* bnn    = (const float*)d_in[23];
  float* ws  = (float*)d_ws;
  float* out = (float*)d_out;

  hipLaunchKernelGGL(k_attn,  dim3(500), dim3(512), 0, stream, cost, rnd, Wv,
                     mix1w, mix1b, mix2w, mix2b, Wo, bo, ws);
  hipLaunchKernelGGL(k_red,   dim3(33),  dim3(256), 0, stream, Wn, Wd, bd, bnn,
                     ws, BN1P, 500, WS_SUM1);
  hipLaunchKernelGGL(k_ffn,   dim3(500), dim3(512), 0, stream, W1, b1, g1, bb1,
                     W2, b2, ws);
  hipLaunchKernelGGL(k_red,   dim3(32),  dim3(256), 0, stream, Wn, Wd, bd, bnn,
                     ws, BN2P, 500, WS_SUM2);
  hipLaunchKernelGGL(k_final, dim3(500), dim3(512), 0, stream, Wn, g2, bb2, dem,
                     out, ws);
}